// Round 4
// baseline (2185.482 us; speedup 1.0000x reference)
//
#include <hip/hip_runtime.h>
#include <hip/hip_bf16.h>

#define B_    16
#define CIN   64
#define Hn    64
#define Wn    64
#define HID   128
#define SPS   264   // sP row stride in shorts (528B = 16B mod 128B -> conflict-free b128)
#define SXS   72    // sX row stride in shorts (144B; rows 16B-aligned for b128 writes)

typedef __attribute__((ext_vector_type(8))) short bfrag_t;   // 8 bf16 (4 VGPRs)
typedef __attribute__((ext_vector_type(4))) float f4_t;

// d_ws layout:
//   [0, 256KB)        : h_buf[0]  bf16 [16][64][128]   (b, w, ci)
//   [256KB, 512KB)    : h_buf[1]  (double buffer: step h writes buf[h&1], reads buf[h&1^1])
//   [512KB, +64B)     : per-b barrier counters (16 x u32), memset to 0 each launch
#define HBUF_SHORTS (B_ * Wn * HID)
#define HBUF_BYTES  (HBUF_SHORTS * 2)

static __device__ __forceinline__ short f2bf(float f) {
    union { __hip_bfloat16 h; short s; } u;
    u.h = __float2bfloat16(f);
    return u.s;
}

extern "C" __global__ __launch_bounds__(256, 1)
void rowlstm_kernel(const float* __restrict__ x,
                    const float* __restrict__ w_is,
                    const float* __restrict__ b_is,
                    const float* __restrict__ w_ss,
                    const float* __restrict__ b_ss,
                    float* __restrict__ out,
                    unsigned char* __restrict__ ws)
{
    const int tid  = threadIdx.x;
    const int bid  = blockIdx.x;
    const int b    = bid >> 4;        // batch
    const int jc   = bid & 15;        // j-chunk: j in [jc*8, jc*8+8)
    const int lane = tid & 63;
    const int wv   = tid >> 6;        // wave id = N-tile (16 w's)
    const int l15  = lane & 15;
    const int quad = lane >> 4;

    short*    hbuf0 = (short*)ws;
    unsigned* cnt   = (unsigned*)(ws + 2 * HBUF_BYTES);

    // LDS: ~50.4 KB total
    __shared__ alignas(16) short sP[Wn * SPS];    // patch matrix, one K-half: [w][256 k +pad] 33KB
    __shared__ alignas(16) short sX[CIN * SXS];   // x row staging [ci][w +pad] (bf16)        9KB
    __shared__ float sZ[32 * 66];                 // z output [lr][w +pad]                    8.25KB
    __shared__ float sBias[32];

    // ---- biases (fp32) ----
    if (tid < 32) {
        int g = tid >> 3, r = tid & 7;
        int co = g * HID + jc * 8 + r;
        sBias[tid] = b_is[co] + b_ss[co];
    }

    // ---- A (weight) fragments -> registers, step-invariant (fp32 -> bf16 once) ----
    // K layout: pass0: [0,128)=x-part (kw*64+ci, kw in {0,1}), [128,256)=h kw0
    //           pass1: [0,128)=h kw1, [128,256)=h kw2
    bfrag_t a_frag[2][2][8];
    {
        #pragma unroll
        for (int p = 0; p < 2; ++p)
        #pragma unroll
        for (int mt = 0; mt < 2; ++mt) {
            int lr = mt * 16 + l15;
            int g = lr >> 3, r = lr & 7;
            int co = g * HID + jc * 8 + r;
            #pragma unroll
            for (int kt = 0; kt < 8; ++kt) {
                bfrag_t v;
                #pragma unroll
                for (int j = 0; j < 8; ++j) {
                    int kk = kt * 32 + quad * 8 + j;   // 0..255
                    float val;
                    if (p == 0) {
                        if (kt < 4) {                  // x-part (masked tap kw=2 excluded)
                            int kw = kk >> 6, ci = kk & 63;
                            val = w_is[(co * CIN + ci) * 3 + kw];
                        } else {                       // h kw0
                            int ci = kk - 128;
                            val = w_ss[(co * HID + ci) * 3 + 0];
                        }
                    } else {
                        if (kt < 4) {                  // h kw1
                            int ci = kk;
                            val = w_ss[(co * HID + ci) * 3 + 1];
                        } else {                       // h kw2
                            int ci = kk - 128;
                            val = w_ss[(co * HID + ci) * 3 + 2];
                        }
                    }
                    v[j] = f2bf(val);
                }
                a_frag[p][mt][kt] = v;
            }
        }
    }

    float creg[2] = {0.f, 0.f};   // LSTM cell state, 2 (jl,w) items per thread
    const int w_c  = tid & 63;    // phase-C item map
    const int jl2  = tid >> 6;

    __syncthreads();

    for (int h = 0; h < Hn; ++h) {
        // step h: read h_{h-1} from rd_buf, write h_h to wr_buf (WAR-safe double buffer)
        const short* rd_hb = hbuf0 + ((h & 1) ^ 1) * HBUF_SHORTS + b * Wn * HID;
        short*       wr_hb = hbuf0 + (h & 1) * HBUF_SHORTS + b * Wn * HID;

        // ================= build pass 0 =================
        {   // stage x row (fp32) -> sX (bf16): each thread 16 consecutive w of one ci
            int ci   = tid >> 2;
            int wseg = (tid & 3) * 16;
            const float* xrow = x + ((b * CIN + ci) * Hn + h) * Wn + wseg;
            f4_t f0 = *(const f4_t*)(xrow + 0);
            f4_t f1 = *(const f4_t*)(xrow + 4);
            f4_t f2 = *(const f4_t*)(xrow + 8);
            f4_t f3 = *(const f4_t*)(xrow + 12);
            bfrag_t v0, v1;
            #pragma unroll
            for (int e = 0; e < 4; ++e) {
                v0[e]     = f2bf(f0[e]);
                v0[e + 4] = f2bf(f1[e]);
                v1[e]     = f2bf(f2[e]);
                v1[e + 4] = f2bf(f3[e]);
            }
            *(bfrag_t*)&sX[ci * SXS + wseg]     = v0;
            *(bfrag_t*)&sX[ci * SXS + wseg + 8] = v1;
        }
        if (h == 0) {
            // h_prev == 0: zero the h-kw0 region for all w
            bfrag_t z8 = {0,0,0,0,0,0,0,0};
            int w = tid >> 2, seg = tid & 3;
            #pragma unroll
            for (int k = 0; k < 4; ++k)
                *(bfrag_t*)&sP[w * SPS + 128 + (seg * 4 + k) * 8] = z8;
        } else {
            // h kw0: P[w'][128+ci] = h[ci][w'-1]  (src w -> dest w+1)
            int cig = tid & 15, w0 = tid >> 4;
            #pragma unroll
            for (int it = 0; it < 4; ++it) {
                int w = w0 + it * 16;
                bfrag_t v = *(const bfrag_t*)(rd_hb + w * HID + cig * 8);
                if (w + 1 < Wn) *(bfrag_t*)&sP[(w + 1) * SPS + 128 + cig * 8] = v;
            }
            if (tid < 16) {
                bfrag_t z8 = {0,0,0,0,0,0,0,0};
                *(bfrag_t*)&sP[128 + tid * 8] = z8;          // sP[0][128..256)
            }
        }
        if (tid >= 16 && tid < 24) {                          // x kw0 boundary: sP[0][0..64)
            bfrag_t z8 = {0,0,0,0,0,0,0,0};
            *(bfrag_t*)&sP[(tid - 16) * 8] = z8;
        }
        __syncthreads();
        {   // transpose sX -> sP x-part: P[w'][kw*64+ci] = x[ci][w'+kw-1]
            int w = tid & 63;
            #pragma unroll
            for (int it = 0; it < 2; ++it) {
                int cig = (tid >> 6) * 2 + it;
                bfrag_t vec;
                #pragma unroll
                for (int e = 0; e < 8; ++e) vec[e] = sX[(cig * 8 + e) * SXS + w];
                if (w + 1 < Wn) *(bfrag_t*)&sP[(w + 1) * SPS + cig * 8] = vec;  // kw0
                *(bfrag_t*)&sP[w * SPS + 64 + cig * 8] = vec;                    // kw1
            }
        }
        __syncthreads();

        // ================= GEMM pass 0 =================
        f4_t acc0 = {0.f, 0.f, 0.f, 0.f};
        f4_t acc1 = {0.f, 0.f, 0.f, 0.f};
        const int pbase = (wv * 16 + l15) * SPS + quad * 8;
        #pragma unroll
        for (int kt = 0; kt < 8; ++kt) {
            bfrag_t bf = *(const bfrag_t*)&sP[pbase + kt * 32];
            acc0 = __builtin_amdgcn_mfma_f32_16x16x32_bf16(a_frag[0][0][kt], bf, acc0, 0, 0, 0);
            acc1 = __builtin_amdgcn_mfma_f32_16x16x32_bf16(a_frag[0][1][kt], bf, acc1, 0, 0, 0);
        }
        __syncthreads();   // done reading sP (pass 0)

        // ================= build pass 1 =================
        if (h == 0) {
            bfrag_t z8 = {0,0,0,0,0,0,0,0};
            int w = tid >> 2, seg = tid & 3;
            #pragma unroll
            for (int k = 0; k < 8; ++k)
                *(bfrag_t*)&sP[w * SPS + (seg * 8 + k) * 8] = z8;
        } else {
            int cig = tid & 15, w0 = tid >> 4;
            #pragma unroll
            for (int it = 0; it < 4; ++it) {
                int w = w0 + it * 16;
                bfrag_t v = *(const bfrag_t*)(rd_hb + w * HID + cig * 8);
                *(bfrag_t*)&sP[w * SPS + cig * 8] = v;                           // kw1
                if (w >= 1) *(bfrag_t*)&sP[(w - 1) * SPS + 128 + cig * 8] = v;   // kw2
            }
            if (tid < 16) {
                bfrag_t z8 = {0,0,0,0,0,0,0,0};
                *(bfrag_t*)&sP[63 * SPS + 128 + tid * 8] = z8;   // sP[63][128..256)
            }
        }
        __syncthreads();

        // ================= GEMM pass 1 =================
        #pragma unroll
        for (int kt = 0; kt < 8; ++kt) {
            bfrag_t bf = *(const bfrag_t*)&sP[pbase + kt * 32];
            acc0 = __builtin_amdgcn_mfma_f32_16x16x32_bf16(a_frag[1][0][kt], bf, acc0, 0, 0, 0);
            acc1 = __builtin_amdgcn_mfma_f32_16x16x32_bf16(a_frag[1][1][kt], bf, acc1, 0, 0, 0);
        }

        // write Z to LDS (C/D layout: row = quad*4+r, col = l15)
        #pragma unroll
        for (int r = 0; r < 4; ++r) {
            sZ[(quad * 4 + r) * 66      + wv * 16 + l15] = acc0[r];
            sZ[(16 + quad * 4 + r) * 66 + wv * 16 + l15] = acc1[r];
        }
        __syncthreads();

        // ================= phase C: gates + cell update =================
        #pragma unroll
        for (int it = 0; it < 2; ++it) {
            int jl = jl2 * 2 + it;
            float z0 = sZ[(jl) * 66 + w_c]      + sBias[jl];
            float z1 = sZ[(8 + jl) * 66 + w_c]  + sBias[8 + jl];
            float z2 = sZ[(16 + jl) * 66 + w_c] + sBias[16 + jl];
            float z3 = sZ[(24 + jl) * 66 + w_c] + sBias[24 + jl];
            float ig = 1.f / (1.f + __expf(-z0));
            float fg = 1.f / (1.f + __expf(-z1));
            float og = 1.f / (1.f + __expf(-z2));
            float gg = 2.f / (1.f + __expf(-2.f * z3)) - 1.f;
            float c  = fg * creg[it] + ig * gg;
            creg[it] = c;
            float th = 2.f / (1.f + __expf(-2.f * c)) - 1.f;
            float hv = og * th;
            out[((b * HID + jc * 8 + jl) * Hn + h) * Wn + w_c] = hv;             // fp32 out
            ((__hip_bfloat16*)wr_hb)[w_c * HID + jc * 8 + jl] = __float2bfloat16(hv);
        }

        // ================= per-b barrier (16 blocks) =================
        if (h < Hn - 1) {
            __syncthreads();   // all h_buf stores issued
            if (tid == 0) {
                __threadfence();   // agent-scope release: drain/writeback before signaling
                __hip_atomic_fetch_add(&cnt[b], 1u, __ATOMIC_RELEASE, __HIP_MEMORY_SCOPE_AGENT);
                unsigned target = (unsigned)(16 * (h + 1));
                while (__hip_atomic_load(&cnt[b], __ATOMIC_ACQUIRE, __HIP_MEMORY_SCOPE_AGENT) < target)
                    __builtin_amdgcn_s_sleep(2);
                __threadfence();   // agent-scope acquire: invalidate stale lines
            }
            __syncthreads();
        }
    }
}

extern "C" void kernel_launch(void* const* d_in, const int* in_sizes, int n_in,
                              void* d_out, int out_size, void* d_ws, size_t ws_size,
                              hipStream_t stream) {
    const float* x    = (const float*)d_in[0];
    const float* w_is = (const float*)d_in[1];
    const float* b_is = (const float*)d_in[2];
    const float* w_ss = (const float*)d_in[3];
    const float* b_ss = (const float*)d_in[4];
    float* out = (float*)d_out;
    unsigned char* ws = (unsigned char*)d_ws;

    // zero the 16 per-b barrier counters
    // (h_buf needs no init: step 0 zero-fills, each buffer written before read)
    hipMemsetAsync(ws + 2 * HBUF_BYTES, 0, 16 * sizeof(unsigned), stream);

    // Plain launch (NOT cooperative). 256 blocks, 50KB LDS -> guaranteed
    // co-residency on 256 CUs; per-b barrier needs only the 16 blocks of one
    // batch co-resident.
    rowlstm_kernel<<<dim3(256), dim3(256), 0, stream>>>(x, w_is, b_is, w_ss, b_ss, out, ws);
}

// Round 5
// 703.798 us; speedup vs baseline: 3.1053x; 3.1053x over previous
//
#include <hip/hip_runtime.h>
#include <hip/hip_bf16.h>

#define B_    16
#define CIN   64
#define Hn    64
#define Wn    64
#define HID   128
#define SPS   264   // sP row stride in shorts (528B = 16B mod 128B -> conflict-free b128)
#define SXS   72    // sX row stride in shorts (144B; rows 16B-aligned for b128 writes)

typedef __attribute__((ext_vector_type(8))) short bfrag_t;   // 8 bf16 (4 VGPRs)
typedef __attribute__((ext_vector_type(4))) float f4_t;

// d_ws layout:
//   [0, 256KB)        : h_buf[0]  bf16 [16][64][128]   (b, w, ci)
//   [256KB, 512KB)    : h_buf[1]  (double buffer: step h writes buf[h&1], reads buf[h&1^1])
//   [512KB, +4KB)     : per-b barrier counters, ONE PER 256B line (memset to 0 each launch)
#define HBUF_SHORTS (B_ * Wn * HID)
#define HBUF_BYTES  (HBUF_SHORTS * 2)
#define CNT_STRIDE  256

static __device__ __forceinline__ short f2bf(float f) {
    union { __hip_bfloat16 h; short s; } u;
    u.h = __float2bfloat16(f);
    return u.s;
}

extern "C" __global__ __launch_bounds__(256, 1)
void rowlstm_kernel(const float* __restrict__ x,
                    const float* __restrict__ w_is,
                    const float* __restrict__ b_is,
                    const float* __restrict__ w_ss,
                    const float* __restrict__ b_ss,
                    float* __restrict__ out,
                    unsigned char* __restrict__ ws)
{
    const int tid  = threadIdx.x;
    const int bid  = blockIdx.x;
    // b = bid & 15: the 16 blocks of batch b have bid % 8 == b % 8 -> same XCD
    // under round-robin dispatch (L2 reuse of x; perf heuristic only).
    const int b    = bid & 15;        // batch
    const int jc   = bid >> 4;        // j-chunk: j in [jc*8, jc*8+8)
    const int lane = tid & 63;
    const int wv   = tid >> 6;        // wave id = N-tile (16 w's)
    const int l15  = lane & 15;
    const int quad = lane >> 4;

    short*    hbuf0 = (short*)ws;
    unsigned* cnt   = (unsigned*)(ws + 2 * HBUF_BYTES + b * CNT_STRIDE);

    // LDS: ~50.4 KB total
    __shared__ alignas(16) short sP[Wn * SPS];    // patch matrix, one K-half: [w][256 k +pad] 33KB
    __shared__ alignas(16) short sX[CIN * SXS];   // x row staging [ci][w +pad] (bf16)        9KB
    __shared__ float sZ[32 * 66];                 // z output [lr][w +pad]                    8.25KB
    __shared__ float sBias[32];

    // ---- biases (fp32) ----
    if (tid < 32) {
        int g = tid >> 3, r = tid & 7;
        int co = g * HID + jc * 8 + r;
        sBias[tid] = b_is[co] + b_ss[co];
    }

    // ---- A (weight) fragments -> registers, step-invariant (fp32 -> bf16 once) ----
    // K layout: pass0: [0,128)=x-part (kw*64+ci, kw in {0,1}), [128,256)=h kw0
    //           pass1: [0,128)=h kw1, [128,256)=h kw2
    bfrag_t a_frag[2][2][8];
    {
        #pragma unroll
        for (int p = 0; p < 2; ++p)
        #pragma unroll
        for (int mt = 0; mt < 2; ++mt) {
            int lr = mt * 16 + l15;
            int g = lr >> 3, r = lr & 7;
            int co = g * HID + jc * 8 + r;
            #pragma unroll
            for (int kt = 0; kt < 8; ++kt) {
                bfrag_t v;
                #pragma unroll
                for (int j = 0; j < 8; ++j) {
                    int kk = kt * 32 + quad * 8 + j;   // 0..255
                    float val;
                    if (p == 0) {
                        if (kt < 4) {                  // x-part (masked tap kw=2 excluded)
                            int kw = kk >> 6, ci = kk & 63;
                            val = w_is[(co * CIN + ci) * 3 + kw];
                        } else {                       // h kw0
                            int ci = kk - 128;
                            val = w_ss[(co * HID + ci) * 3 + 0];
                        }
                    } else {
                        if (kt < 4) {                  // h kw1
                            int ci = kk;
                            val = w_ss[(co * HID + ci) * 3 + 1];
                        } else {                       // h kw2
                            int ci = kk - 128;
                            val = w_ss[(co * HID + ci) * 3 + 2];
                        }
                    }
                    v[j] = f2bf(val);
                }
                a_frag[p][mt][kt] = v;
            }
        }
    }

    float creg[2] = {0.f, 0.f};   // LSTM cell state, 2 (jl,w) items per thread
    const int w_c  = tid & 63;    // phase-C item map
    const int jl2  = tid >> 6;

    // x staging geometry (per thread: 16 consecutive w of one ci)
    const int ci_x   = tid >> 2;
    const int wseg_x = (tid & 3) * 16;

    // prefetch x row 0 into registers
    f4_t xf0, xf1, xf2, xf3;
    {
        const float* xrow = x + ((b * CIN + ci_x) * Hn + 0) * Wn + wseg_x;
        xf0 = *(const f4_t*)(xrow + 0);
        xf1 = *(const f4_t*)(xrow + 4);
        xf2 = *(const f4_t*)(xrow + 8);
        xf3 = *(const f4_t*)(xrow + 12);
    }

    __syncthreads();

    for (int h = 0; h < Hn; ++h) {
        // step h: read h_{h-1} from rd_buf, write h_h to wr_buf (WAR-safe double buffer)
        const short* rd_hb = hbuf0 + ((h & 1) ^ 1) * HBUF_SHORTS + b * Wn * HID;
        short*       wr_hb = hbuf0 + (h & 1) * HBUF_SHORTS + b * Wn * HID;

        // ================= build pass 0 =================
        {   // convert prefetched x row -> sX (bf16)
            bfrag_t v0, v1;
            #pragma unroll
            for (int e = 0; e < 4; ++e) {
                v0[e]     = f2bf(xf0[e]);
                v0[e + 4] = f2bf(xf1[e]);
                v1[e]     = f2bf(xf2[e]);
                v1[e + 4] = f2bf(xf3[e]);
            }
            *(bfrag_t*)&sX[ci_x * SXS + wseg_x]     = v0;
            *(bfrag_t*)&sX[ci_x * SXS + wseg_x + 8] = v1;
        }
        bfrag_t hreg[4];   // pass-0 h loads, reused in pass 1 (same addresses)
        if (h == 0) {
            // h_prev == 0: zero the h-kw0 region for all w
            bfrag_t z8 = {0,0,0,0,0,0,0,0};
            int w = tid >> 2, seg = tid & 3;
            #pragma unroll
            for (int k = 0; k < 4; ++k)
                *(bfrag_t*)&sP[w * SPS + 128 + (seg * 4 + k) * 8] = z8;
        } else {
            // h kw0: P[w'][128+ci] = h[ci][w'-1]  (src w -> dest w+1)
            int cig = tid & 15, w0 = tid >> 4;
            #pragma unroll
            for (int it = 0; it < 4; ++it) {
                int w = w0 + it * 16;
                hreg[it] = *(const bfrag_t*)(rd_hb + w * HID + cig * 8);
                if (w + 1 < Wn) *(bfrag_t*)&sP[(w + 1) * SPS + 128 + cig * 8] = hreg[it];
            }
            if (tid < 16) {
                bfrag_t z8 = {0,0,0,0,0,0,0,0};
                *(bfrag_t*)&sP[128 + tid * 8] = z8;          // sP[0][128..256)
            }
        }
        if (tid >= 16 && tid < 24) {                          // x kw0 boundary: sP[0][0..64)
            bfrag_t z8 = {0,0,0,0,0,0,0,0};
            *(bfrag_t*)&sP[(tid - 16) * 8] = z8;
        }
        __syncthreads();
        {   // transpose sX -> sP x-part: P[w'][kw*64+ci] = x[ci][w'+kw-1]
            int w = tid & 63;
            #pragma unroll
            for (int it = 0; it < 2; ++it) {
                int cig = (tid >> 6) * 2 + it;
                bfrag_t vec;
                #pragma unroll
                for (int e = 0; e < 8; ++e) vec[e] = sX[(cig * 8 + e) * SXS + w];
                if (w + 1 < Wn) *(bfrag_t*)&sP[(w + 1) * SPS + cig * 8] = vec;  // kw0
                *(bfrag_t*)&sP[w * SPS + 64 + cig * 8] = vec;                    // kw1
            }
        }
        __syncthreads();

        // ================= GEMM pass 0 =================
        f4_t acc0 = {0.f, 0.f, 0.f, 0.f};
        f4_t acc1 = {0.f, 0.f, 0.f, 0.f};
        const int pbase = (wv * 16 + l15) * SPS + quad * 8;
        #pragma unroll
        for (int kt = 0; kt < 8; ++kt) {
            bfrag_t bf = *(const bfrag_t*)&sP[pbase + kt * 32];
            acc0 = __builtin_amdgcn_mfma_f32_16x16x32_bf16(a_frag[0][0][kt], bf, acc0, 0, 0, 0);
            acc1 = __builtin_amdgcn_mfma_f32_16x16x32_bf16(a_frag[0][1][kt], bf, acc1, 0, 0, 0);
        }
        __syncthreads();   // done reading sP (pass 0)

        // ================= build pass 1 =================
        if (h == 0) {
            bfrag_t z8 = {0,0,0,0,0,0,0,0};
            int w = tid >> 2, seg = tid & 3;
            #pragma unroll
            for (int k = 0; k < 8; ++k)
                *(bfrag_t*)&sP[w * SPS + (seg * 8 + k) * 8] = z8;
        } else {
            int cig = tid & 15, w0 = tid >> 4;
            #pragma unroll
            for (int it = 0; it < 4; ++it) {
                int w = w0 + it * 16;
                *(bfrag_t*)&sP[w * SPS + cig * 8] = hreg[it];                           // kw1
                if (w >= 1) *(bfrag_t*)&sP[(w - 1) * SPS + 128 + cig * 8] = hreg[it];   // kw2
            }
            if (tid < 16) {
                bfrag_t z8 = {0,0,0,0,0,0,0,0};
                *(bfrag_t*)&sP[63 * SPS + 128 + tid * 8] = z8;   // sP[63][128..256)
            }
        }
        __syncthreads();

        // ================= GEMM pass 1 =================
        #pragma unroll
        for (int kt = 0; kt < 8; ++kt) {
            bfrag_t bf = *(const bfrag_t*)&sP[pbase + kt * 32];
            acc0 = __builtin_amdgcn_mfma_f32_16x16x32_bf16(a_frag[1][0][kt], bf, acc0, 0, 0, 0);
            acc1 = __builtin_amdgcn_mfma_f32_16x16x32_bf16(a_frag[1][1][kt], bf, acc1, 0, 0, 0);
        }

        // write Z to LDS (C/D layout: row = quad*4+r, col = l15)
        #pragma unroll
        for (int r = 0; r < 4; ++r) {
            sZ[(quad * 4 + r) * 66      + wv * 16 + l15] = acc0[r];
            sZ[(16 + quad * 4 + r) * 66 + wv * 16 + l15] = acc1[r];
        }
        __syncthreads();

        // ================= phase C: gates + cell update =================
        #pragma unroll
        for (int it = 0; it < 2; ++it) {
            int jl = jl2 * 2 + it;
            float z0 = sZ[(jl) * 66 + w_c]      + sBias[jl];
            float z1 = sZ[(8 + jl) * 66 + w_c]  + sBias[8 + jl];
            float z2 = sZ[(16 + jl) * 66 + w_c] + sBias[16 + jl];
            float z3 = sZ[(24 + jl) * 66 + w_c] + sBias[24 + jl];
            float ig = 1.f / (1.f + __expf(-z0));
            float fg = 1.f / (1.f + __expf(-z1));
            float og = 1.f / (1.f + __expf(-z2));
            float gg = 2.f / (1.f + __expf(-2.f * z3)) - 1.f;
            float c  = fg * creg[it] + ig * gg;
            creg[it] = c;
            float th = 2.f / (1.f + __expf(-2.f * c)) - 1.f;
            float hv = og * th;
            out[((b * HID + jc * 8 + jl) * Hn + h) * Wn + w_c] = hv;             // fp32 out
            ((__hip_bfloat16*)wr_hb)[w_c * HID + jc * 8 + jl] = __float2bfloat16(hv);
        }

        // ================= per-b barrier (16 blocks) =================
        if (h < Hn - 1) {
            // prefetch next x row; loads stay in flight across the barrier
            {
                const float* xrow = x + ((b * CIN + ci_x) * Hn + (h + 1)) * Wn + wseg_x;
                xf0 = *(const f4_t*)(xrow + 0);
                xf1 = *(const f4_t*)(xrow + 4);
                xf2 = *(const f4_t*)(xrow + 8);
                xf3 = *(const f4_t*)(xrow + 12);
            }
            __syncthreads();   // all h_buf stores issued block-wide
            if (tid == 0) {
                // release RMW publishes this block's h_buf stores (agent scope)
                __hip_atomic_fetch_add(cnt, 1u, __ATOMIC_RELEASE, __HIP_MEMORY_SCOPE_AGENT);
                unsigned target = (unsigned)(16 * (h + 1));
                // RELAXED polls: agent-scope access reads the coherence point
                // without a per-iteration cache invalidate
                while (__hip_atomic_load(cnt, __ATOMIC_RELAXED, __HIP_MEMORY_SCOPE_AGENT) < target)
                    __builtin_amdgcn_s_sleep(4);
                // one acquire fence: invalidate stale L1/L2 before peers' h is read
                __builtin_amdgcn_fence(__ATOMIC_ACQUIRE, "agent");
            }
            __syncthreads();
        }
    }
}

extern "C" void kernel_launch(void* const* d_in, const int* in_sizes, int n_in,
                              void* d_out, int out_size, void* d_ws, size_t ws_size,
                              hipStream_t stream) {
    const float* x    = (const float*)d_in[0];
    const float* w_is = (const float*)d_in[1];
    const float* b_is = (const float*)d_in[2];
    const float* w_ss = (const float*)d_in[3];
    const float* b_ss = (const float*)d_in[4];
    float* out = (float*)d_out;
    unsigned char* ws = (unsigned char*)d_ws;

    // zero the padded per-b barrier counters (16 x 256B)
    hipMemsetAsync(ws + 2 * HBUF_BYTES, 0, B_ * CNT_STRIDE, stream);

    // Plain launch (NOT cooperative). 256 blocks, 50KB LDS -> co-residency on
    // 256 CUs; per-b barrier needs only the 16 blocks of one batch co-resident.
    rowlstm_kernel<<<dim3(256), dim3(256), 0, stream>>>(x, w_is, b_is, w_ss, b_ss, out, ws);
}

// Round 6
// 318.954 us; speedup vs baseline: 6.8520x; 2.2066x over previous
//
#include <hip/hip_runtime.h>
#include <hip/hip_bf16.h>

#define B_    16
#define CIN   64
#define Hn    64
#define Wn    64
#define HID   128
#define SXS2  72    // sX2 row stride in shorts (144B, 16B-aligned)
#define SHS   136   // sH  row stride in shorts (272B, 16B-aligned)

typedef __attribute__((ext_vector_type(8))) short bfrag_t;   // 8 bf16 (4 VGPRs)
typedef __attribute__((ext_vector_type(4))) float f4_t;

// d_ws layout:
//   [0, 256KB)        : h_buf[0]  bf16 [16][64][128]   (b, w, ci)
//   [256KB, 512KB)    : h_buf[1]  (double buffer: step h writes buf[h&1], reads buf[h&1^1])
//   [512KB, +4KB)     : per-b barrier counters, one per 256B line
#define HBUF_SHORTS (B_ * Wn * HID)
#define HBUF_BYTES  (HBUF_SHORTS * 2)
#define CNT_STRIDE  256

static __device__ __forceinline__ short f2bf(float f) {
    union { __hip_bfloat16 h; short s; } u;
    u.h = __float2bfloat16(f);
    return u.s;
}

extern "C" __global__ __launch_bounds__(256, 1)
void rowlstm_kernel(const float* __restrict__ x,
                    const float* __restrict__ w_is,
                    const float* __restrict__ b_is,
                    const float* __restrict__ w_ss,
                    const float* __restrict__ b_ss,
                    float* __restrict__ out,
                    unsigned char* __restrict__ ws)
{
    const int tid  = threadIdx.x;
    const int bid  = blockIdx.x;
    // b = bid & 15: the 16 blocks of batch b share bid%8 -> same XCD under
    // round-robin dispatch (L2 locality heuristic only; correctness-safe).
    const int b    = bid & 15;        // batch
    const int jc   = bid >> 4;        // j-chunk: j in [jc*8, jc*8+8)
    const int lane = tid & 63;
    const int wv   = tid >> 6;        // wave id = N-tile (16 w's)
    const int l15  = lane & 15;
    const int quad = lane >> 4;

    short*    hbuf0 = (short*)ws;
    unsigned* cnt   = (unsigned*)(ws + 2 * HBUF_BYTES + b * CNT_STRIDE);

    // LDS ~36 KB. Shifted-read panels: tap t of column w' reads row w'+t.
    __shared__ alignas(16) short sH[66 * SHS];    // h panel, rows 0..65 (0,65 = zero guards)
    __shared__ alignas(16) short sX2[65 * SXS2];  // x panel, rows 0..64 (0 = zero guard)
    __shared__ float sZ[32 * 66];                 // z output [lr][w +pad]
    __shared__ float sBias[32];

    if (tid < 32) {
        int g = tid >> 3, r = tid & 7;
        int co = g * HID + jc * 8 + r;
        sBias[tid] = b_is[co] + b_ss[co];
    }

    // ---- A (weight) fragments, step-invariant. K layout (512):
    // [0,64) x kw0 | [64,128) x kw1 | [128,256) h kw0 | [256,384) h kw1 | [384,512) h kw2
    bfrag_t a_frag[2][16];
    #pragma unroll
    for (int mt = 0; mt < 2; ++mt) {
        int lr = mt * 16 + l15;
        int g = lr >> 3, r = lr & 7;
        int co = g * HID + jc * 8 + r;
        #pragma unroll
        for (int kt = 0; kt < 16; ++kt) {
            bfrag_t v;
            #pragma unroll
            for (int j = 0; j < 8; ++j) {
                int kk = kt * 32 + quad * 8 + j;   // 0..511
                float val;
                if      (kk < 64)  val = w_is[(co * CIN + kk) * 3 + 0];
                else if (kk < 128) val = w_is[(co * CIN + (kk - 64)) * 3 + 1];
                else if (kk < 256) val = w_ss[(co * HID + (kk - 128)) * 3 + 0];
                else if (kk < 384) val = w_ss[(co * HID + (kk - 256)) * 3 + 1];
                else               val = w_ss[(co * HID + (kk - 384)) * 3 + 2];
                v[j] = f2bf(val);
            }
            a_frag[mt][kt] = v;
        }
    }

    // zero guard rows (never touched again)
    {
        bfrag_t z8 = {0,0,0,0,0,0,0,0};
        if (tid < 8)  *(bfrag_t*)&sX2[tid * 8] = z8;                 // sX2 row 0 (64 ci)
        if (tid < 16) {
            *(bfrag_t*)&sH[tid * 8] = z8;                            // sH row 0
            *(bfrag_t*)&sH[65 * SHS + tid * 8] = z8;                 // sH row 65
        }
    }

    float creg[2] = {0.f, 0.f};
    const int w_c = tid & 63;     // phase-C column
    const int jl2 = tid >> 6;

    // x staging: thread (xw, xc2) holds x[ci = xc2*16 .. +15][xw] for the current row
    const int xw  = tid & 63;
    const int xc2 = tid >> 6;
    float xr[16];
    #pragma unroll
    for (int e = 0; e < 16; ++e)
        xr[e] = x[((b * CIN + xc2 * 16 + e) * Hn + 0) * Wn + xw];

    __syncthreads();

    for (int h = 0; h < Hn; ++h) {
        const short* rd_hb = hbuf0 + ((h & 1) ^ 1) * HBUF_SHORTS + b * Wn * HID;
        short*       wr_hb = hbuf0 + (h & 1) * HBUF_SHORTS + b * Wn * HID;

        // ---- build x panel: row xw+1 = x[.][xw] (single copy; taps read shifted) ----
        {
            bfrag_t v0, v1;
            #pragma unroll
            for (int e = 0; e < 8; ++e) { v0[e] = f2bf(xr[e]); v1[e] = f2bf(xr[e + 8]); }
            *(bfrag_t*)&sX2[(xw + 1) * SXS2 + xc2 * 16]     = v0;
            *(bfrag_t*)&sX2[(xw + 1) * SXS2 + xc2 * 16 + 8] = v1;
        }
        // ---- build h panel: row w+1 = h_prev[.][w] via LLC-coherent loads ----
        {
            int cig = tid & 15, w0 = tid >> 4;
            #pragma unroll
            for (int it = 0; it < 4; ++it) {
                int w = w0 + it * 16;
                union { bfrag_t f; unsigned long long q[2]; } u;
                if (h == 0) { u.q[0] = 0ull; u.q[1] = 0ull; }
                else {
                    const unsigned long long* src =
                        (const unsigned long long*)(rd_hb + w * HID + cig * 8);
                    u.q[0] = __hip_atomic_load(src,     __ATOMIC_RELAXED, __HIP_MEMORY_SCOPE_AGENT);
                    u.q[1] = __hip_atomic_load(src + 1, __ATOMIC_RELAXED, __HIP_MEMORY_SCOPE_AGENT);
                }
                *(bfrag_t*)&sH[(w + 1) * SHS + cig * 8] = u.f;
            }
        }
        __syncthreads();   // S1: panels ready

        // ---- GEMM, single pass K=512 ----
        f4_t acc0 = {0.f, 0.f, 0.f, 0.f};
        f4_t acc1 = {0.f, 0.f, 0.f, 0.f};
        const int wp = wv * 16 + l15;
        #pragma unroll
        for (int kt = 0; kt < 16; ++kt) {
            const short* src;
            if (kt < 4) {                         // x taps: t = kt>>1
                src = &sX2[(wp + (kt >> 1)) * SXS2 + (kt & 1) * 32 + quad * 8];
            } else {                              // h taps: t = (kt-4)>>2
                src = &sH[(wp + ((kt - 4) >> 2)) * SHS + ((kt - 4) & 3) * 32 + quad * 8];
            }
            bfrag_t bf = *(const bfrag_t*)src;
            acc0 = __builtin_amdgcn_mfma_f32_16x16x32_bf16(a_frag[0][kt], bf, acc0, 0, 0, 0);
            acc1 = __builtin_amdgcn_mfma_f32_16x16x32_bf16(a_frag[1][kt], bf, acc1, 0, 0, 0);
        }
        // C/D layout: row = quad*4+r, col = l15
        #pragma unroll
        for (int r = 0; r < 4; ++r) {
            sZ[(quad * 4 + r) * 66      + wp] = acc0[r];
            sZ[(16 + quad * 4 + r) * 66 + wp] = acc1[r];
        }
        __syncthreads();   // S2: sZ ready

        // ---- phase C: gates + cell update ----
        {
            float hv2[2];
            #pragma unroll
            for (int it = 0; it < 2; ++it) {
                int jl = jl2 * 2 + it;
                float z0 = sZ[(jl) * 66 + w_c]      + sBias[jl];
                float z1 = sZ[(8 + jl) * 66 + w_c]  + sBias[8 + jl];
                float z2 = sZ[(16 + jl) * 66 + w_c] + sBias[16 + jl];
                float z3 = sZ[(24 + jl) * 66 + w_c] + sBias[24 + jl];
                float ig = 1.f / (1.f + __expf(-z0));
                float fg = 1.f / (1.f + __expf(-z1));
                float og = 1.f / (1.f + __expf(-z2));
                float gg = 2.f / (1.f + __expf(-2.f * z3)) - 1.f;
                float c  = fg * creg[it] + ig * gg;
                creg[it] = c;
                float th = 2.f / (1.f + __expf(-2.f * c)) - 1.f;
                hv2[it]  = og * th;
                out[((b * HID + jc * 8 + jl) * Hn + h) * Wn + w_c] = hv2[it];
            }
            // packed bf16 pair -> LLC write-through (agent-scope relaxed atomic)
            unsigned pk = (unsigned)(unsigned short)f2bf(hv2[0]) |
                          ((unsigned)(unsigned short)f2bf(hv2[1]) << 16);
            unsigned* dst = (unsigned*)(wr_hb + w_c * HID + jc * 8 + jl2 * 2);
            __hip_atomic_store(dst, pk, __ATOMIC_RELAXED, __HIP_MEMORY_SCOPE_AGENT);
        }
        // prefetch next x row; loads stay in flight across the barrier
        {
            int hp = (h < Hn - 1) ? h + 1 : h;
            #pragma unroll
            for (int e = 0; e < 16; ++e)
                xr[e] = x[((b * CIN + xc2 * 16 + e) * Hn + hp) * Wn + xw];
        }
        __syncthreads();   // S3: phase C done; vmcnt drained -> h stores at LLC

        // ---- per-b barrier, fence-free (all cross-block data goes via LLC) ----
        if (h < Hn - 1) {
            if (tid == 0) {
                __hip_atomic_fetch_add(cnt, 1u, __ATOMIC_RELAXED, __HIP_MEMORY_SCOPE_AGENT);
                unsigned target = (unsigned)(16 * (h + 1));
                while (__hip_atomic_load(cnt, __ATOMIC_RELAXED, __HIP_MEMORY_SCOPE_AGENT) < target)
                    __builtin_amdgcn_s_sleep(2);
            }
            __syncthreads();   // S4: release block into next step
        }
    }
}

extern "C" void kernel_launch(void* const* d_in, const int* in_sizes, int n_in,
                              void* d_out, int out_size, void* d_ws, size_t ws_size,
                              hipStream_t stream) {
    const float* x    = (const float*)d_in[0];
    const float* w_is = (const float*)d_in[1];
    const float* b_is = (const float*)d_in[2];
    const float* w_ss = (const float*)d_in[3];
    const float* b_ss = (const float*)d_in[4];
    float* out = (float*)d_out;
    unsigned char* ws = (unsigned char*)d_ws;

    hipMemsetAsync(ws + 2 * HBUF_BYTES, 0, B_ * CNT_STRIDE, stream);

    // Plain launch; 256 blocks, 36KB LDS, 1 block/CU -> all co-resident.
    rowlstm_kernel<<<dim3(256), dim3(256), 0, stream>>>(x, w_is, b_is, w_ss, b_ss, out, ws);
}